// Round 15
// baseline (803.149 us; speedup 1.0000x reference)
//
#include <hip/hip_runtime.h>
#include <cstdint>

// ---------------------------------------------------------------------------
// Red-black SOR Laplace solver, persistent kernel. Round 15: 3 planes/block
// (44 blocks). Authoritative f64 state for planes 3b..3b+2 in LDS; interior
// plane 3b+1 never touches global. Cross-block traffic: packed f32 halves of
// the two boundary planes only (pre-filled constants + gm-only inline
// publish, c = o>>1). Neighbor-flag ordering (unchanged from r13/r14):
//   black(t) stages pr[(t-1)&1][z0-1, z0+3]  guarded by red-flag[b+-1] >= t-1
//   red(t)   stages pb[t&1][z0-1, z0+3]      guarded by black-flag[b+-1] >= t
// Stop: depth-8 dv ring (fixed-point payload), polled for g=t-2 at start of
// iter t in parallel with the flag wait; exact uniform dv -> uniform stop;
// reports iters=149 and dv(149) exactly (1 extra iteration computed).
// Cross z-neighbors are f32-rounded (r14-proven); interior are f64.
// ---------------------------------------------------------------------------

#define NBLK 44
#define NTHR 1024
#define NW   (NTHR / 64)

constexpr int NJK   = 66;
constexpr int PLANE = 66 * 66;          // 4356
constexpr int HPL   = PLANE / 2;        // 2178 packed entries per half
constexpr int NI    = 132;
constexpr int CAPL  = 2048;             // max gm per color per plane
constexpr int NOUT  = 2 * 64 * 64 * 64; // 524288
// ctrl 128B lines: [0..127] dv rings 0..7 (16 lines each); [128..143]
// startup barrier; [144..275] black flags (144+b); [276..407] red flags.
constexpr int CTRL_U64 = 408 * 16;
constexpr unsigned long long CNT1   = 1ull << 44;
constexpr unsigned long long MASK44 = CNT1 - 1ull;

__global__ void sor_init_ctrl(unsigned long long* ctrl) {
  for (int i = threadIdx.x; i < CTRL_U64; i += blockDim.x) ctrl[i] = 0ull;
}

__device__ __forceinline__ float cloadf(const float* p) {
  return __hip_atomic_load(p, __ATOMIC_RELAXED, __HIP_MEMORY_SCOPE_AGENT);
}
__device__ __forceinline__ void cstoref(float* p, float v) {
  __hip_atomic_store(p, v, __ATOMIC_RELAXED, __HIP_MEMORY_SCOPE_AGENT);
}
__device__ __forceinline__ unsigned long long cloadu(const unsigned long long* p) {
  return __hip_atomic_load(p, __ATOMIC_RELAXED, __HIP_MEMORY_SCOPE_AGENT);
}
__device__ __forceinline__ void cstoreu(unsigned long long* p, unsigned long long v) {
  __hip_atomic_store(p, v, __ATOMIC_RELAXED, __HIP_MEMORY_SCOPE_AGENT);
}

// padded flat coords -> original image flat index, or -1 if pad voxel
__device__ __forceinline__ int pad_label_idx(int ii, int jj, int kk) {
  int b  = (ii >= 66) ? 1 : 0;
  int pz = ii - 66 * b;
  if (pz < 1 || pz > 64 || jj < 1 || jj > 64 || kk < 1 || kk > 64) return -1;
  return ((b * 64 + (pz - 1)) * 64 + (jj - 1)) * 64 + (kk - 1);
}

__global__ __launch_bounds__(NTHR, 1)
void sor_main(const float* __restrict__ img,
              float* __restrict__ pb0, float* __restrict__ pb1,
              float* __restrict__ pr0, float* __restrict__ pr1,
              unsigned long long* __restrict__ ctrl,
              float* __restrict__ out) {
  __shared__ double P[3][PLANE];             // planes 3b, 3b+1, 3b+2 (f64)
  __shared__ unsigned short ls[3][2][CAPL];  // [plane][color] voxel offsets
  __shared__ unsigned wsum[NW], woff[NW];
  __shared__ unsigned tot;
  __shared__ unsigned cnts[3][2];
  __shared__ double redw[NW];
  __shared__ unsigned long long prevs[8];
  __shared__ double sh_dv;

  const int tid = threadIdx.x, bid = blockIdx.x;
  const int lane = tid & 63, wid = tid >> 6;
  const int z0 = 3 * bid;

  // ---- init 3 planes in LDS ----
  for (int s = 0; s < 3; ++s) {
    const int z = z0 + s;
    for (int o = tid; o < PLANE; o += NTHR) {
      int j = o / NJK, k = o - j * NJK;
      int li = pad_label_idx(z, j, k);
      float L = (li >= 0) ? img[li] : 0.0f;
      P[s][o] = (L == 3.0f) ? 1.0 : 0.0;
    }
  }
  if (tid < 8) prevs[tid] = 0ull;

  // ---- build gm lists per plane x color (stable o-order) ----
  const int CH = (PLANE + NTHR - 1) / NTHR;
  for (int s = 0; s < 3; ++s) {
    const int z = z0 + s;
    for (int cb = 0; cb < 2; ++cb) {
      unsigned short* list = ls[s][cb];
      int c0 = tid * CH;
      int c1 = (c0 + CH < PLANE) ? (c0 + CH) : PLANE;
      unsigned cnt = 0;
      for (int o = c0; o < c1; ++o) {
        int j = o / NJK, k = o - j * NJK;
        if (((z + j + k) & 1) != cb) continue;
        int li = pad_label_idx(z, j, k);
        float L = (li >= 0) ? img[li] : 0.0f;
        if (L == 1.0f) cnt++;
      }
      unsigned incl = cnt;
      #pragma unroll
      for (int m = 1; m < 64; m <<= 1) {
        unsigned t = __shfl_up(incl, m, 64);
        if (lane >= m) incl += t;
      }
      __syncthreads();
      if (lane == 63) wsum[wid] = incl;
      __syncthreads();
      if (tid == 0) {
        unsigned a = 0;
        for (int w = 0; w < NW; ++w) { unsigned c = wsum[w]; woff[w] = a; a += c; }
        tot = a;
      }
      __syncthreads();
      unsigned p = (incl - cnt) + woff[wid];
      for (int o = c0; o < c1; ++o) {
        int j = o / NJK, k = o - j * NJK;
        if (((z + j + k) & 1) != cb) continue;
        int li = pad_label_idx(z, j, k);
        float L = (li >= 0) ? img[li] : 0.0f;
        if (L == 1.0f) list[p++] = (unsigned short)o;
      }
      __syncthreads();
      if (tid == 0) cnts[s][cb] = tot;
      __syncthreads();
    }
  }
  const int cB0 = (int)cnts[0][0], cB1 = (int)cnts[1][0], cB2 = (int)cnts[2][0];
  const int cR0 = (int)cnts[0][1], cR1 = (int)cnts[1][1], cR2 = (int)cnts[2][1];

  // ---- pre-fill packed halves of BOUNDARY planes into all 4 buffers ----
  for (int s = 0; s < 3; s += 2) {
    const int z = z0 + s;
    for (int c = tid; c < HPL; c += NTHR) {
      int j = c / 33, m = c - 33 * j;
      int kb = (m << 1) + ((z + j) & 1);        // black positions
      int kr = (m << 1) + ((z + j + 1) & 1);    // red positions
      float vb = (float)P[s][NJK * j + kb];
      float vr = (float)P[s][NJK * j + kr];
      cstoref(&pb0[(size_t)z * HPL + c], vb);
      cstoref(&pb1[(size_t)z * HPL + c], vb);
      cstoref(&pr0[(size_t)z * HPL + c], vr);
      cstoref(&pr1[(size_t)z * HPL + c], vr);
    }
  }
  __syncthreads();                         // drain pre-fill
  // ---- startup barrier (count-only, 16 lines) ----
  if (tid == 0)
    __hip_atomic_fetch_add(&ctrl[(128u + (unsigned)(bid & 15)) * 16u], 1ull,
                           __ATOMIC_RELAXED, __HIP_MEMORY_SCOPE_AGENT);
  if (tid < 16) {
    for (;;) {
      unsigned long long v = cloadu(&ctrl[(128u + (unsigned)tid) * 16u]);
      v += __shfl_xor(v, 1, 64);  v += __shfl_xor(v, 2, 64);
      v += __shfl_xor(v, 4, 64);  v += __shfl_xor(v, 8, 64);
      if (v >= (unsigned long long)NBLK) break;
      __builtin_amdgcn_s_sleep(1);
    }
  }
  __syncthreads();

  const double WOPT = 2.0 / (1.0 + 3.14159265358979323846 / 66.0);

  int itout = 0;
  double dvout = 0.0;

  for (int t = 1; t <= 555; ++t) {
    const float* __restrict__ prold = (t & 1) ? pr0 : pr1;  // pr[(t-1)&1]
    float* __restrict__ pbcur       = (t & 1) ? pb1 : pb0;  // pb[t&1]
    float* __restrict__ prcur       = (t & 1) ? pr1 : pr0;  // pr[t&1]

    // ---- start-of-iter parallel waits + lagged stop decision ----
    if (t > 1) {
      const int g = t - 2;
      if (wid == 0 && lane < 2) {           // wave 0: neighbor red flags
        int nb = (lane == 0) ? (bid - 1) : (bid + 1);
        if (nb >= 0 && nb < NBLK) {
          while (cloadu(&ctrl[(276u + (unsigned)nb) * 16u])
                 < (unsigned long long)(t - 1))
            __builtin_amdgcn_s_sleep(1);
        }
      }
      if (g >= 1 && wid == 1 && lane < 16) { // wave 1: dv ring poll
        const int r = g & 7;
        const unsigned n = ((unsigned)g + 7u) >> 3;
        const unsigned long long t64 =
            ((unsigned long long)NBLK * n) << 44;
        unsigned long long v;
        for (;;) {
          v = cloadu(&ctrl[((unsigned)r * 16u + (unsigned)lane) * 16u]);
          v += __shfl_xor(v, 1, 64);  v += __shfl_xor(v, 2, 64);
          v += __shfl_xor(v, 4, 64);  v += __shfl_xor(v, 8, 64);
          if (v >= t64) break;
          __builtin_amdgcn_s_sleep(1);
        }
        if (lane == 0) {
          unsigned long long cum = v & MASK44;
          sh_dv = (double)(cum - prevs[r]) * (1.0 / 1048576.0);
          prevs[r] = cum;
        }
      }
      __syncthreads();
      if (g >= 1) {
        double dvg = sh_dv;
        if (!((dvg >= 0.05) && (g <= 500))) { itout = g; dvout = dvg; break; }
      }
    }

    double acc = 0.0;
    // ================= BLACK sweep =================
    {
      const float* __restrict__ rmz =
          (z0 > 0) ? (prold + (size_t)(z0 - 1) * HPL) : prold;
      const float* __restrict__ rpz =
          (z0 + 3 < NI) ? (prold + (size_t)(z0 + 3) * HPL) : prold;
      // stage cross loads for boundary planes (<= 2 per thread per plane)
      float g0a = 0, g0b = 0, g2a = 0, g2b = 0;
      int o0a = -1, o0b = -1, o2a = -1, o2b = -1;
      if (tid < cB0)        { o0a = (int)ls[0][0][tid];
                              g0a = cloadf(&rmz[o0a >> 1]); }
      if (tid + 1024 < cB0) { o0b = (int)ls[0][0][tid + 1024];
                              g0b = cloadf(&rmz[o0b >> 1]); }
      if (tid < cB2)        { o2a = (int)ls[2][0][tid];
                              g2a = cloadf(&rpz[o2a >> 1]); }
      if (tid + 1024 < cB2) { o2b = (int)ls[2][0][tid + 1024];
                              g2b = cloadf(&rpz[o2b >> 1]); }
      // interior plane black (pure LDS) — hides staged-load latency
      for (int p = tid; p < cB1; p += NTHR) {
        const int o = (int)ls[1][0][p];
        double xi = P[1][o];
        double nb = ((((P[1][o - 1] + P[1][o + 1]) + P[1][o - NJK])
                    + P[1][o + NJK]) + P[0][o]) + P[2][o];
        double adj = (WOPT * (nb - 6.0 * xi)) / 6.0;
        P[1][o] = xi + adj;
        acc += fabs(adj);
      }
      // boundary plane 0 black + inline publish
      float* __restrict__ pbz0 = pbcur + (size_t)z0 * HPL;
      if (o0a >= 0) {
        const int o = o0a;
        double xi = P[0][o];
        double nb = ((((P[0][o - 1] + P[0][o + 1]) + P[0][o - NJK])
                    + P[0][o + NJK]) + (double)g0a) + P[1][o];
        double adj = (WOPT * (nb - 6.0 * xi)) / 6.0;
        double v = xi + adj;
        P[0][o] = v;
        cstoref(&pbz0[o >> 1], (float)v);
        acc += fabs(adj);
      }
      if (o0b >= 0) {
        const int o = o0b;
        double xi = P[0][o];
        double nb = ((((P[0][o - 1] + P[0][o + 1]) + P[0][o - NJK])
                    + P[0][o + NJK]) + (double)g0b) + P[1][o];
        double adj = (WOPT * (nb - 6.0 * xi)) / 6.0;
        double v = xi + adj;
        P[0][o] = v;
        cstoref(&pbz0[o >> 1], (float)v);
        acc += fabs(adj);
      }
      // boundary plane 2 black + inline publish
      float* __restrict__ pbz2 = pbcur + (size_t)(z0 + 2) * HPL;
      if (o2a >= 0) {
        const int o = o2a;
        double xi = P[2][o];
        double nb = ((((P[2][o - 1] + P[2][o + 1]) + P[2][o - NJK])
                    + P[2][o + NJK]) + P[1][o]) + (double)g2a;
        double adj = (WOPT * (nb - 6.0 * xi)) / 6.0;
        double v = xi + adj;
        P[2][o] = v;
        cstoref(&pbz2[o >> 1], (float)v);
        acc += fabs(adj);
      }
      if (o2b >= 0) {
        const int o = o2b;
        double xi = P[2][o];
        double nb = ((((P[2][o - 1] + P[2][o + 1]) + P[2][o - NJK])
                    + P[2][o + NJK]) + P[1][o]) + (double)g2b;
        double adj = (WOPT * (nb - 6.0 * xi)) / 6.0;
        double v = xi + adj;
        P[2][o] = v;
        cstoref(&pbz2[o >> 1], (float)v);
        acc += fabs(adj);
      }
    }
    __syncthreads();                       // LDS visible + publishes drained
    if (tid == 0)
      cstoreu(&ctrl[(144u + (unsigned)bid) * 16u], (unsigned long long)t);
    if (tid < 2) {                         // wait neighbors' black publish
      int nb = (tid == 0) ? (bid - 1) : (bid + 1);
      if (nb >= 0 && nb < NBLK) {
        while (cloadu(&ctrl[(144u + (unsigned)nb) * 16u])
               < (unsigned long long)t)
          __builtin_amdgcn_s_sleep(1);
      }
    }
    __syncthreads();

    // ================= RED sweep =================
    {
      const float* __restrict__ bmz =
          (z0 > 0) ? (pbcur + (size_t)(z0 - 1) * HPL) : pbcur;
      const float* __restrict__ bpz =
          (z0 + 3 < NI) ? (pbcur + (size_t)(z0 + 3) * HPL) : pbcur;
      float g0a = 0, g0b = 0, g2a = 0, g2b = 0;
      int o0a = -1, o0b = -1, o2a = -1, o2b = -1;
      if (tid < cR0)        { o0a = (int)ls[0][1][tid];
                              g0a = cloadf(&bmz[o0a >> 1]); }
      if (tid + 1024 < cR0) { o0b = (int)ls[0][1][tid + 1024];
                              g0b = cloadf(&bmz[o0b >> 1]); }
      if (tid < cR2)        { o2a = (int)ls[2][1][tid];
                              g2a = cloadf(&bpz[o2a >> 1]); }
      if (tid + 1024 < cR2) { o2b = (int)ls[2][1][tid + 1024];
                              g2b = cloadf(&bpz[o2b >> 1]); }
      // interior plane red (pure LDS)
      for (int p = tid; p < cR1; p += NTHR) {
        const int o = (int)ls[1][1][p];
        double xi = P[1][o];
        double nb = ((((P[1][o - 1] + P[1][o + 1]) + P[1][o - NJK])
                    + P[1][o + NJK]) + P[0][o]) + P[2][o];
        double adj = (WOPT * (nb - 6.0 * xi)) / 6.0;
        P[1][o] = xi + adj;
        acc += fabs(adj);
      }
      // boundary plane 0 red + inline publish
      float* __restrict__ prz0 = prcur + (size_t)z0 * HPL;
      if (o0a >= 0) {
        const int o = o0a;
        double xi = P[0][o];
        double nb = ((((P[0][o - 1] + P[0][o + 1]) + P[0][o - NJK])
                    + P[0][o + NJK]) + (double)g0a) + P[1][o];
        double adj = (WOPT * (nb - 6.0 * xi)) / 6.0;
        double v = xi + adj;
        P[0][o] = v;
        cstoref(&prz0[o >> 1], (float)v);
        acc += fabs(adj);
      }
      if (o0b >= 0) {
        const int o = o0b;
        double xi = P[0][o];
        double nb = ((((P[0][o - 1] + P[0][o + 1]) + P[0][o - NJK])
                    + P[0][o + NJK]) + (double)g0b) + P[1][o];
        double adj = (WOPT * (nb - 6.0 * xi)) / 6.0;
        double v = xi + adj;
        P[0][o] = v;
        cstoref(&prz0[o >> 1], (float)v);
        acc += fabs(adj);
      }
      // boundary plane 2 red + inline publish
      float* __restrict__ prz2 = prcur + (size_t)(z0 + 2) * HPL;
      if (o2a >= 0) {
        const int o = o2a;
        double xi = P[2][o];
        double nb = ((((P[2][o - 1] + P[2][o + 1]) + P[2][o - NJK])
                    + P[2][o + NJK]) + P[1][o]) + (double)g2a;
        double adj = (WOPT * (nb - 6.0 * xi)) / 6.0;
        double v = xi + adj;
        P[2][o] = v;
        cstoref(&prz2[o >> 1], (float)v);
        acc += fabs(adj);
      }
      if (o2b >= 0) {
        const int o = o2b;
        double xi = P[2][o];
        double nb = ((((P[2][o - 1] + P[2][o + 1]) + P[2][o - NJK])
                    + P[2][o + NJK]) + P[1][o]) + (double)g2b;
        double adj = (WOPT * (nb - 6.0 * xi)) / 6.0;
        double v = xi + adj;
        P[2][o] = v;
        cstoref(&prz2[o >> 1], (float)v);
        acc += fabs(adj);
      }
    }

    // ---- block dv reduce (fixed order) + flag + ring post ----
    double a = acc;
    #pragma unroll
    for (int m = 32; m >= 1; m >>= 1) a += __shfl_xor(a, m, 64);
    if (lane == 0) redw[wid] = a;
    __syncthreads();                       // drains red publish; redw ready
    if (tid == 0) {
      double s = redw[0];
      #pragma unroll
      for (int w = 1; w < NW; ++w) s += redw[w];
      cstoreu(&ctrl[(276u + (unsigned)bid) * 16u], (unsigned long long)t);
      __hip_atomic_fetch_add(
          &ctrl[(((unsigned)t & 7u) * 16u + (unsigned)(bid & 15)) * 16u],
          CNT1 + (unsigned long long)(s * 1048576.0 + 0.5),
          __ATOMIC_RELAXED, __HIP_MEMORY_SCOPE_AGENT);
    }
  }

  // ---- epilogue: lap straight from LDS (crop pad), + iters + dv ----
  for (int s = 0; s < 3; ++s) {
    const int z = z0 + s;
    const int vb = (z >= 66) ? 1 : 0;
    const int pz = z - 66 * vb;
    if (pz >= 1 && pz <= 64) {
      float* ob = out + ((size_t)vb * 64 + (pz - 1)) * 4096;
      for (int t2 = tid; t2 < 4096; t2 += NTHR) {
        int jj = t2 >> 6, kk = t2 & 63;
        ob[t2] = (float)P[s][NJK * (jj + 1) + (kk + 1)];
      }
    }
  }
  if (bid == 0 && tid == 0) {
    out[NOUT]     = (float)itout;
    out[NOUT + 1] = (float)dvout;
  }
}

extern "C" void kernel_launch(void* const* d_in, const int* in_sizes, int n_in,
                              void* d_out, int out_size, void* d_ws, size_t ws_size,
                              hipStream_t stream) {
  const float* img = (const float*)d_in[0];
  float* out = (float*)d_out;
  float* pb0 = (float*)d_ws;
  float* pb1 = pb0 + (size_t)NI * HPL;
  float* pr0 = pb1 + (size_t)NI * HPL;
  float* pr1 = pr0 + (size_t)NI * HPL;
  unsigned long long* ctrl = (unsigned long long*)(pr1 + (size_t)NI * HPL);

  sor_init_ctrl<<<1, 256, 0, stream>>>(ctrl);
  sor_main<<<NBLK, NTHR, 0, stream>>>(img, pb0, pb1, pr0, pr1, ctrl, out);
}

// Round 16
// 707.373 us; speedup vs baseline: 1.1354x; 1.1354x over previous
//
#include <hip/hip_runtime.h>
#include <cstdint>

// ---------------------------------------------------------------------------
// Red-black SOR Laplace solver, persistent kernel. Round 16: DENSE minimal
// exchange. 2 planes/block (66 blocks), authoritative f64 planes in LDS.
// Both sides of each interface compute (from img) the identical o-ordered
// set {o: gm(z,o) && gm(z+-1,o)} of cross-dependent positions; the exchange
// is a dense f32 array indexed by list position (slot). Cross positions that
// are non-gm are CONSTANT (0/1) and folded into per-voxel const lists
// (bit-identical to r14's prefilled-buffer loads). Per plane x color:
//   lsD (dyn): read cross dense[p], publish own value to dense[p]
//   lsC (const): value in the entry, no global access
// Interface i sits between planes 2i-1 (side L, block i-1 plane1) and 2i
// (side H, block i plane0). Channels: pb/pr (black/red published values),
// parity-2, [iface][side][SLOT] dense f32.
// Sync protocol identical to r13/r14 (passed, iters=149): neighbor flag
// chain + depth-8 dv ring with fixed-point payload, parallel start-waits,
// lagged stop at g=t-2; reports iters=149 and dv(149) exactly.
// ---------------------------------------------------------------------------

#define NBLK 66
#define NTHR 1024
#define NW   (NTHR / 64)

constexpr int NJK   = 66;
constexpr int PLANE = 66 * 66;          // 4356
constexpr int NI    = 132;
constexpr int CAPD  = 512;              // dyn cap (mean ~136)
constexpr int CAPC  = 1024;             // const cap (mean ~409)
constexpr int SLOT  = 512;              // dense slots per channel
constexpr int NIF   = 67;               // interfaces 0..66
constexpr int NOUT  = 2 * 64 * 64 * 64; // 524288
// ctrl 128B lines: [0..127] dv rings 0..7 (16 lines each); [128..143]
// startup barrier; [144..275] black flags (144+b); [276..407] red flags.
constexpr int CTRL_U64 = 408 * 16;
constexpr unsigned long long CNT1   = 1ull << 44;
constexpr unsigned long long MASK44 = CNT1 - 1ull;

__global__ void sor_init_ctrl(unsigned long long* ctrl) {
  for (int i = threadIdx.x; i < CTRL_U64; i += blockDim.x) ctrl[i] = 0ull;
}

__device__ __forceinline__ float cloadf(const float* p) {
  return __hip_atomic_load(p, __ATOMIC_RELAXED, __HIP_MEMORY_SCOPE_AGENT);
}
__device__ __forceinline__ void cstoref(float* p, float v) {
  __hip_atomic_store(p, v, __ATOMIC_RELAXED, __HIP_MEMORY_SCOPE_AGENT);
}
__device__ __forceinline__ unsigned long long cloadu(const unsigned long long* p) {
  return __hip_atomic_load(p, __ATOMIC_RELAXED, __HIP_MEMORY_SCOPE_AGENT);
}
__device__ __forceinline__ void cstoreu(unsigned long long* p, unsigned long long v) {
  __hip_atomic_store(p, v, __ATOMIC_RELAXED, __HIP_MEMORY_SCOPE_AGENT);
}

// padded flat coords -> original image flat index, or -1 if pad voxel
__device__ __forceinline__ int pad_label_idx(int ii, int jj, int kk) {
  int b  = (ii >= 66) ? 1 : 0;
  int pz = ii - 66 * b;
  if (pz < 1 || pz > 64 || jj < 1 || jj > 64 || kk < 1 || kk > 64) return -1;
  return ((b * 64 + (pz - 1)) * 64 + (jj - 1)) * 64 + (kk - 1);
}

__global__ __launch_bounds__(NTHR, 1)
void sor_main(const float* __restrict__ img,
              float* __restrict__ pb0, float* __restrict__ pb1,
              float* __restrict__ pr0, float* __restrict__ pr1,
              unsigned long long* __restrict__ ctrl,
              float* __restrict__ out) {
  __shared__ double P[2][PLANE];               // planes 2b, 2b+1 (f64)
  __shared__ unsigned short lsD[2][2][CAPD];   // dyn: [plane][color] -> o
  __shared__ unsigned lsC[2][2][CAPC];         // const: o | (val<<16)
  __shared__ unsigned wsum[NW], woff[NW];
  __shared__ unsigned tot;
  __shared__ unsigned cntS[2][2][2];           // [plane][color][cat]
  __shared__ double redw[NW];
  __shared__ unsigned long long prevs[8];
  __shared__ double sh_dv;

  const int tid = threadIdx.x, bid = blockIdx.x;
  const int lane = tid & 63, wid = tid >> 6;
  const int z0 = 2 * bid;

  // ---- init 2 planes in LDS ----
  for (int s = 0; s < 2; ++s) {
    const int z = z0 + s;
    for (int o = tid; o < PLANE; o += NTHR) {
      int j = o / NJK, k = o - j * NJK;
      int li = pad_label_idx(z, j, k);
      float L = (li >= 0) ? img[li] : 0.0f;
      P[s][o] = (L == 3.0f) ? 1.0 : 0.0;
    }
  }
  if (tid < 8) prevs[tid] = 0ull;

  // ---- build dyn/const lists per plane x color (stable o-order) ----
  const int CH = (PLANE + NTHR - 1) / NTHR;
  for (int s = 0; s < 2; ++s) {
    const int z  = z0 + s;
    const int zx = (s == 0) ? (z0 - 1) : (z0 + 2);   // cross plane
    for (int cb = 0; cb < 2; ++cb) {
      for (int cat = 0; cat < 2; ++cat) {            // 0 = dyn, 1 = const
        int c0 = tid * CH;
        int c1 = (c0 + CH < PLANE) ? (c0 + CH) : PLANE;
        unsigned cnt = 0;
        for (int o = c0; o < c1; ++o) {
          int j = o / NJK, k = o - j * NJK;
          if (((z + j + k) & 1) != cb) continue;
          int li = pad_label_idx(z, j, k);
          float L = (li >= 0) ? img[li] : 0.0f;
          if (L != 1.0f) continue;
          int lxi = pad_label_idx(zx, j, k);
          float Lx = (lxi >= 0) ? img[lxi] : 0.0f;
          bool xg = (Lx == 1.0f);
          if ((cat == 0) == xg) cnt++;
        }
        unsigned incl = cnt;
        #pragma unroll
        for (int m = 1; m < 64; m <<= 1) {
          unsigned t = __shfl_up(incl, m, 64);
          if (lane >= m) incl += t;
        }
        __syncthreads();
        if (lane == 63) wsum[wid] = incl;
        __syncthreads();
        if (tid == 0) {
          unsigned a = 0;
          for (int w = 0; w < NW; ++w) { unsigned c = wsum[w]; woff[w] = a; a += c; }
          tot = a;
        }
        __syncthreads();
        unsigned p = (incl - cnt) + woff[wid];
        for (int o = c0; o < c1; ++o) {
          int j = o / NJK, k = o - j * NJK;
          if (((z + j + k) & 1) != cb) continue;
          int li = pad_label_idx(z, j, k);
          float L = (li >= 0) ? img[li] : 0.0f;
          if (L != 1.0f) continue;
          int lxi = pad_label_idx(zx, j, k);
          float Lx = (lxi >= 0) ? img[lxi] : 0.0f;
          bool xg = (Lx == 1.0f);
          if ((cat == 0) != xg) continue;
          if (cat == 0) lsD[s][cb][p++] = (unsigned short)o;
          else          lsC[s][cb][p++] = (unsigned)o |
                                          ((Lx == 3.0f ? 1u : 0u) << 16);
        }
        __syncthreads();
        if (tid == 0) cntS[s][cb][cat] = tot;
        __syncthreads();
      }
    }
  }
  const int nD00 = (int)cntS[0][0][0], nC00 = (int)cntS[0][0][1];
  const int nD01 = (int)cntS[0][1][0], nC01 = (int)cntS[0][1][1];
  const int nD10 = (int)cntS[1][0][0], nC10 = (int)cntS[1][0][1];
  const int nD11 = (int)cntS[1][1][0], nC11 = (int)cntS[1][1][1];

  // ---- channel offsets: [iface][side] * SLOT ----
  const size_t off_p0 = ((size_t)bid * 2 + 1) * SLOT;        // plane0 pub (H)
  const size_t off_p1 = ((size_t)(bid + 1) * 2 + 0) * SLOT;  // plane1 pub (L)
  const size_t off_r0 = ((size_t)bid * 2 + 0) * SLOT;        // plane0 read (L)
  const size_t off_r1 = ((size_t)(bid + 1) * 2 + 1) * SLOT;  // plane1 read (H)

  // ---- prefill initial red dyn values into pr0 and pr1 ----
  for (int p = tid; p < nD01; p += NTHR) {
    float v = (float)P[0][lsD[0][1][p]];
    cstoref(&pr0[off_p0 + p], v); cstoref(&pr1[off_p0 + p], v);
  }
  for (int p = tid; p < nD11; p += NTHR) {
    float v = (float)P[1][lsD[1][1][p]];
    cstoref(&pr0[off_p1 + p], v); cstoref(&pr1[off_p1 + p], v);
  }
  __syncthreads();                         // drain prefill
  // ---- startup barrier (count-only, 16 lines) ----
  if (tid == 0)
    __hip_atomic_fetch_add(&ctrl[(128u + (unsigned)(bid & 15)) * 16u], 1ull,
                           __ATOMIC_RELAXED, __HIP_MEMORY_SCOPE_AGENT);
  if (tid < 16) {
    for (;;) {
      unsigned long long v = cloadu(&ctrl[(128u + (unsigned)tid) * 16u]);
      v += __shfl_xor(v, 1, 64);  v += __shfl_xor(v, 2, 64);
      v += __shfl_xor(v, 4, 64);  v += __shfl_xor(v, 8, 64);
      if (v >= (unsigned long long)NBLK) break;
      __builtin_amdgcn_s_sleep(1);
    }
  }
  __syncthreads();

  const double WOPT = 2.0 / (1.0 + 3.14159265358979323846 / 66.0);

  int itout = 0;
  double dvout = 0.0;

  for (int t = 1; t <= 555; ++t) {
    const float* __restrict__ prold = (t & 1) ? pr0 : pr1;  // pr[(t-1)&1]
    float* __restrict__ pbcur       = (t & 1) ? pb1 : pb0;  // pb[t&1]
    float* __restrict__ prcur       = (t & 1) ? pr1 : pr0;  // pr[t&1]

    // ---- start-of-iter parallel waits + lagged stop decision ----
    if (t > 1) {
      const int g = t - 2;
      if (wid == 0 && lane < 2) {           // wave 0: neighbor red flags
        int nb = (lane == 0) ? (bid - 1) : (bid + 1);
        if (nb >= 0 && nb < NBLK) {
          while (cloadu(&ctrl[(276u + (unsigned)nb) * 16u])
                 < (unsigned long long)(t - 1))
            __builtin_amdgcn_s_sleep(1);
        }
      }
      if (g >= 1 && wid == 1 && lane < 16) { // wave 1: dv ring poll
        const int r = g & 7;
        const unsigned n = ((unsigned)g + 7u) >> 3;
        const unsigned long long t64 =
            ((unsigned long long)NBLK * n) << 44;
        unsigned long long v;
        for (;;) {
          v = cloadu(&ctrl[((unsigned)r * 16u + (unsigned)lane) * 16u]);
          v += __shfl_xor(v, 1, 64);  v += __shfl_xor(v, 2, 64);
          v += __shfl_xor(v, 4, 64);  v += __shfl_xor(v, 8, 64);
          if (v >= t64) break;
          __builtin_amdgcn_s_sleep(1);
        }
        if (lane == 0) {
          unsigned long long cum = v & MASK44;
          sh_dv = (double)(cum - prevs[r]) * (1.0 / 1048576.0);
          prevs[r] = cum;
        }
      }
      __syncthreads();
      if (g >= 1) {
        double dvg = sh_dv;
        if (!((dvg >= 0.05) && (g <= 500))) { itout = g; dvout = dvg; break; }
      }
    }

    double acc = 0.0;
    // ================= BLACK sweep =================
    {
      const float* __restrict__ rd0 = prold + off_r0;
      const float* __restrict__ rd1 = prold + off_r1;
      float* __restrict__ wr0 = pbcur + off_p0;
      float* __restrict__ wr1 = pbcur + off_p1;
      float g0 = 0, g1 = 0; int o0 = -1, o1 = -1;
      if (tid < nD00) { o0 = (int)lsD[0][0][tid]; g0 = cloadf(&rd0[tid]); }
      if (tid < nD10) { o1 = (int)lsD[1][0][tid]; g1 = cloadf(&rd1[tid]); }
      for (int p = tid; p < nC00; p += NTHR) {
        unsigned u = lsC[0][0][p]; int o = (int)(u & 0xFFFFu);
        double xi = P[0][o];
        double nb = ((((P[0][o - 1] + P[0][o + 1]) + P[0][o - NJK])
                    + P[0][o + NJK]) + (double)(u >> 16)) + P[1][o];
        double adj = (WOPT * (nb - 6.0 * xi)) / 6.0;
        P[0][o] = xi + adj;
        acc += fabs(adj);
      }
      for (int p = tid; p < nC10; p += NTHR) {
        unsigned u = lsC[1][0][p]; int o = (int)(u & 0xFFFFu);
        double xi = P[1][o];
        double nb = ((((P[1][o - 1] + P[1][o + 1]) + P[1][o - NJK])
                    + P[1][o + NJK]) + P[0][o]) + (double)(u >> 16);
        double adj = (WOPT * (nb - 6.0 * xi)) / 6.0;
        P[1][o] = xi + adj;
        acc += fabs(adj);
      }
      if (o0 >= 0) {
        const int o = o0;
        double xi = P[0][o];
        double nb = ((((P[0][o - 1] + P[0][o + 1]) + P[0][o - NJK])
                    + P[0][o + NJK]) + (double)g0) + P[1][o];
        double adj = (WOPT * (nb - 6.0 * xi)) / 6.0;
        double v = xi + adj;
        P[0][o] = v;
        cstoref(&wr0[tid], (float)v);
        acc += fabs(adj);
      }
      if (o1 >= 0) {
        const int o = o1;
        double xi = P[1][o];
        double nb = ((((P[1][o - 1] + P[1][o + 1]) + P[1][o - NJK])
                    + P[1][o + NJK]) + P[0][o]) + (double)g1;
        double adj = (WOPT * (nb - 6.0 * xi)) / 6.0;
        double v = xi + adj;
        P[1][o] = v;
        cstoref(&wr1[tid], (float)v);
        acc += fabs(adj);
      }
    }
    __syncthreads();                       // LDS visible + publishes drained
    if (tid == 0)
      cstoreu(&ctrl[(144u + (unsigned)bid) * 16u], (unsigned long long)t);
    if (tid < 2) {                         // wait neighbors' black publish
      int nb = (tid == 0) ? (bid - 1) : (bid + 1);
      if (nb >= 0 && nb < NBLK) {
        while (cloadu(&ctrl[(144u + (unsigned)nb) * 16u])
               < (unsigned long long)t)
          __builtin_amdgcn_s_sleep(1);
      }
    }
    __syncthreads();

    // ================= RED sweep =================
    {
      const float* __restrict__ rr0 = pbcur + off_r0;
      const float* __restrict__ rr1 = pbcur + off_r1;
      float* __restrict__ wq0 = prcur + off_p0;
      float* __restrict__ wq1 = prcur + off_p1;
      float g0 = 0, g1 = 0; int o0 = -1, o1 = -1;
      if (tid < nD01) { o0 = (int)lsD[0][1][tid]; g0 = cloadf(&rr0[tid]); }
      if (tid < nD11) { o1 = (int)lsD[1][1][tid]; g1 = cloadf(&rr1[tid]); }
      for (int p = tid; p < nC01; p += NTHR) {
        unsigned u = lsC[0][1][p]; int o = (int)(u & 0xFFFFu);
        double xi = P[0][o];
        double nb = ((((P[0][o - 1] + P[0][o + 1]) + P[0][o - NJK])
                    + P[0][o + NJK]) + (double)(u >> 16)) + P[1][o];
        double adj = (WOPT * (nb - 6.0 * xi)) / 6.0;
        P[0][o] = xi + adj;
        acc += fabs(adj);
      }
      for (int p = tid; p < nC11; p += NTHR) {
        unsigned u = lsC[1][1][p]; int o = (int)(u & 0xFFFFu);
        double xi = P[1][o];
        double nb = ((((P[1][o - 1] + P[1][o + 1]) + P[1][o - NJK])
                    + P[1][o + NJK]) + P[0][o]) + (double)(u >> 16);
        double adj = (WOPT * (nb - 6.0 * xi)) / 6.0;
        P[1][o] = xi + adj;
        acc += fabs(adj);
      }
      if (o0 >= 0) {
        const int o = o0;
        double xi = P[0][o];
        double nb = ((((P[0][o - 1] + P[0][o + 1]) + P[0][o - NJK])
                    + P[0][o + NJK]) + (double)g0) + P[1][o];
        double adj = (WOPT * (nb - 6.0 * xi)) / 6.0;
        double v = xi + adj;
        P[0][o] = v;
        cstoref(&wq0[tid], (float)v);
        acc += fabs(adj);
      }
      if (o1 >= 0) {
        const int o = o1;
        double xi = P[1][o];
        double nb = ((((P[1][o - 1] + P[1][o + 1]) + P[1][o - NJK])
                    + P[1][o + NJK]) + P[0][o]) + (double)g1;
        double adj = (WOPT * (nb - 6.0 * xi)) / 6.0;
        double v = xi + adj;
        P[1][o] = v;
        cstoref(&wq1[tid], (float)v);
        acc += fabs(adj);
      }
    }

    // ---- block dv reduce (fixed order) + flag + ring post ----
    double a = acc;
    #pragma unroll
    for (int m = 32; m >= 1; m >>= 1) a += __shfl_xor(a, m, 64);
    if (lane == 0) redw[wid] = a;
    __syncthreads();                       // drains red publish; redw ready
    if (tid == 0) {
      double s = redw[0];
      #pragma unroll
      for (int w = 1; w < NW; ++w) s += redw[w];
      cstoreu(&ctrl[(276u + (unsigned)bid) * 16u], (unsigned long long)t);
      __hip_atomic_fetch_add(
          &ctrl[(((unsigned)t & 7u) * 16u + (unsigned)(bid & 15)) * 16u],
          CNT1 + (unsigned long long)(s * 1048576.0 + 0.5),
          __ATOMIC_RELAXED, __HIP_MEMORY_SCOPE_AGENT);
    }
  }

  // ---- epilogue: lap straight from LDS (crop pad), + iters + dv ----
  for (int s = 0; s < 2; ++s) {
    const int z = z0 + s;
    const int vb = (z >= 66) ? 1 : 0;
    const int pz = z - 66 * vb;
    if (pz >= 1 && pz <= 64) {
      float* ob = out + ((size_t)vb * 64 + (pz - 1)) * 4096;
      for (int t2 = tid; t2 < 4096; t2 += NTHR) {
        int jj = t2 >> 6, kk = t2 & 63;
        ob[t2] = (float)P[s][NJK * (jj + 1) + (kk + 1)];
      }
    }
  }
  if (bid == 0 && tid == 0) {
    out[NOUT]     = (float)itout;
    out[NOUT + 1] = (float)dvout;
  }
}

extern "C" void kernel_launch(void* const* d_in, const int* in_sizes, int n_in,
                              void* d_out, int out_size, void* d_ws, size_t ws_size,
                              hipStream_t stream) {
  const float* img = (const float*)d_in[0];
  float* out = (float*)d_out;
  const size_t CH_ELEMS = (size_t)NIF * 2 * SLOT;
  float* pb0 = (float*)d_ws;
  float* pb1 = pb0 + CH_ELEMS;
  float* pr0 = pb1 + CH_ELEMS;
  float* pr1 = pr0 + CH_ELEMS;
  unsigned long long* ctrl = (unsigned long long*)(pr1 + CH_ELEMS);

  sor_init_ctrl<<<1, 256, 0, stream>>>(ctrl);
  sor_main<<<NBLK, NTHR, 0, stream>>>(img, pb0, pb1, pr0, pr1, ctrl, out);
}

// Round 17
// 663.566 us; speedup vs baseline: 1.2104x; 1.0660x over previous
//
#include <hip/hip_runtime.h>
#include <cstdint>

// ---------------------------------------------------------------------------
// Red-black SOR Laplace solver, persistent kernel. Round 17 = r14's
// 1-plane/block structure (132 blocks; best sync/compute balance) + r16's
// DENSE minimal exchange (traffic ~0).
// Per interface i (planes i-1 | i): both sides enumerate the symmetric set
// {o: gm(i-1,o) && gm(i,o)} in identical o-order -> READ SLOT == PUBLISH
// SLOT. Each gm voxel carries a u32 aux: two 15-bit codes (dir z-1, dir
// z+1): dense slot if cross-gm, else 0x8000|const(0/1). Sweeps stage the
// two dense arrays into LDS, compute crosses from codes, and publish the
// updated value inline through the same codes. Channels: pb/pr (values
// published by black/red sweeps), parity-2, [iface][side][SLOT] f32.
// Black sweep publishes black-dyn slots; neighbor red sweep reads exactly
// those slots (cross parity flips with z). Values are bit-identical to
// r14's packed-buffer reads (f32-rounded published values / const 0,1),
// same op order, same dv fixed-point path -> iters = 149 as r14.
// Sync: r14's neighbor flag chain + depth-8 dv ring, parallel start-waits,
// lagged exact stop at g = t-2 (1 extra iteration computed; reports
// iters=149 and dv(149) exactly).
// ---------------------------------------------------------------------------

#define NBLK 132
#define NTHR 1024
#define NW   (NTHR / 64)

constexpr int NJK   = 66;
constexpr int PLANE = 66 * 66;          // 4356
constexpr int NI    = 132;
constexpr int CAPL  = 2048;             // max gm per color per plane
constexpr int SLOT  = 768;              // dense slots per channel (mean ~256)
constexpr int NIF   = 133;              // interfaces 0..132
constexpr int NOUT  = 2 * 64 * 64 * 64; // 524288
// ctrl 128B lines: [0..127] dv rings 0..7 (16 lines each); [128..143]
// startup barrier; [144..275] black flags (144+b); [276..407] red flags.
constexpr int CTRL_U64 = 408 * 16;
constexpr unsigned long long CNT1   = 1ull << 44;
constexpr unsigned long long MASK44 = CNT1 - 1ull;

__global__ void sor_init_ctrl(unsigned long long* ctrl) {
  for (int i = threadIdx.x; i < CTRL_U64; i += blockDim.x) ctrl[i] = 0ull;
}

__device__ __forceinline__ float cloadf(const float* p) {
  return __hip_atomic_load(p, __ATOMIC_RELAXED, __HIP_MEMORY_SCOPE_AGENT);
}
__device__ __forceinline__ void cstoref(float* p, float v) {
  __hip_atomic_store(p, v, __ATOMIC_RELAXED, __HIP_MEMORY_SCOPE_AGENT);
}
__device__ __forceinline__ unsigned long long cloadu(const unsigned long long* p) {
  return __hip_atomic_load(p, __ATOMIC_RELAXED, __HIP_MEMORY_SCOPE_AGENT);
}
__device__ __forceinline__ void cstoreu(unsigned long long* p, unsigned long long v) {
  __hip_atomic_store(p, v, __ATOMIC_RELAXED, __HIP_MEMORY_SCOPE_AGENT);
}

// padded flat coords -> original image flat index, or -1 if pad voxel
__device__ __forceinline__ int pad_label_idx(int ii, int jj, int kk) {
  int b  = (ii >= 66) ? 1 : 0;
  int pz = ii - 66 * b;
  if (pz < 1 || pz > 64 || jj < 1 || jj > 64 || kk < 1 || kk > 64) return -1;
  return ((b * 64 + (pz - 1)) * 64 + (jj - 1)) * 64 + (kk - 1);
}

__global__ __launch_bounds__(NTHR, 1)
void sor_main(const float* __restrict__ img,
              float* __restrict__ pb0, float* __restrict__ pb1,
              float* __restrict__ pr0, float* __restrict__ pr1,
              unsigned long long* __restrict__ ctrl,
              float* __restrict__ out) {
  __shared__ double P1[PLANE];                 // own plane, f64
  __shared__ unsigned short tmpm[PLANE];       // dense slot map, dir z-1
  __shared__ unsigned short tmpp[PLANE];       // dense slot map, dir z+1
  __shared__ unsigned short lsB[CAPL], lsR[CAPL];
  __shared__ unsigned auxB[CAPL], auxR[CAPL];  // codem | (codep<<16)
  __shared__ float HM[SLOT], HP[SLOT];         // staged dense cross arrays
  __shared__ unsigned wsum[NW], woff[NW];
  __shared__ unsigned tot;
  __shared__ double redw[NW];
  __shared__ unsigned long long prevs[8];
  __shared__ double sh_dv;

  const int tid = threadIdx.x, bid = blockIdx.x;
  const int lane = tid & 63, wid = tid >> 6;
  const int z = bid;

  // ---- init own plane in LDS ----
  for (int o = tid; o < PLANE; o += NTHR) {
    int j = o / NJK, k = o - j * NJK;
    int li = pad_label_idx(z, j, k);
    float L = (li >= 0) ? img[li] : 0.0f;
    P1[o] = (L == 3.0f) ? 1.0 : 0.0;
  }
  if (tid < 8) prevs[tid] = 0ull;

  const int CH = (PLANE + NTHR - 1) / NTHR;
  // ---- passes A/B: dense slot maps per direction (both colors, o-order) --
  int nM = 0, nP = 0;
  for (int dir = 0; dir < 2; ++dir) {
    const int zx = (dir == 0) ? (z - 1) : (z + 1);
    unsigned short* tmp = (dir == 0) ? tmpm : tmpp;
    int c0 = tid * CH;
    int c1 = (c0 + CH < PLANE) ? (c0 + CH) : PLANE;
    unsigned cnt = 0;
    for (int o = c0; o < c1; ++o) {
      int j = o / NJK, k = o - j * NJK;
      int li = pad_label_idx(z, j, k);
      float L = (li >= 0) ? img[li] : 0.0f;
      if (L != 1.0f) continue;
      int lx = pad_label_idx(zx, j, k);
      float Lx = (lx >= 0) ? img[lx] : 0.0f;
      if (Lx == 1.0f) cnt++;
    }
    unsigned incl = cnt;
    #pragma unroll
    for (int m = 1; m < 64; m <<= 1) {
      unsigned t = __shfl_up(incl, m, 64);
      if (lane >= m) incl += t;
    }
    __syncthreads();
    if (lane == 63) wsum[wid] = incl;
    __syncthreads();
    if (tid == 0) {
      unsigned a = 0;
      for (int w = 0; w < NW; ++w) { unsigned c = wsum[w]; woff[w] = a; a += c; }
      tot = a;
    }
    __syncthreads();
    unsigned p = (incl - cnt) + woff[wid];
    for (int o = c0; o < c1; ++o) {
      int j = o / NJK, k = o - j * NJK;
      int li = pad_label_idx(z, j, k);
      float L = (li >= 0) ? img[li] : 0.0f;
      if (L != 1.0f) continue;
      int lx = pad_label_idx(zx, j, k);
      float Lx = (lx >= 0) ? img[lx] : 0.0f;
      if (Lx == 1.0f) tmp[o] = (unsigned short)(p++);
    }
    __syncthreads();
    if (dir == 0) nM = (int)tot; else nP = (int)tot;
  }

  // ---- pass C: per-color gm lists + aux codes (stable o-order) ----
  int cntB = 0, cntR = 0;
  for (int cb = 0; cb < 2; ++cb) {
    unsigned short* list = (cb == 0) ? lsB : lsR;
    unsigned* aux        = (cb == 0) ? auxB : auxR;
    int c0 = tid * CH;
    int c1 = (c0 + CH < PLANE) ? (c0 + CH) : PLANE;
    unsigned cnt = 0;
    for (int o = c0; o < c1; ++o) {
      int j = o / NJK, k = o - j * NJK;
      if (((z + j + k) & 1) != cb) continue;
      int li = pad_label_idx(z, j, k);
      float L = (li >= 0) ? img[li] : 0.0f;
      if (L == 1.0f) cnt++;
    }
    unsigned incl = cnt;
    #pragma unroll
    for (int m = 1; m < 64; m <<= 1) {
      unsigned t = __shfl_up(incl, m, 64);
      if (lane >= m) incl += t;
    }
    __syncthreads();
    if (lane == 63) wsum[wid] = incl;
    __syncthreads();
    if (tid == 0) {
      unsigned a = 0;
      for (int w = 0; w < NW; ++w) { unsigned c = wsum[w]; woff[w] = a; a += c; }
      tot = a;
    }
    __syncthreads();
    unsigned p = (incl - cnt) + woff[wid];
    for (int o = c0; o < c1; ++o) {
      int j = o / NJK, k = o - j * NJK;
      if (((z + j + k) & 1) != cb) continue;
      int li = pad_label_idx(z, j, k);
      float L = (li >= 0) ? img[li] : 0.0f;
      if (L != 1.0f) continue;
      int lm = pad_label_idx(z - 1, j, k);
      float Lm = (lm >= 0) ? img[lm] : 0.0f;
      int lp = pad_label_idx(z + 1, j, k);
      float Lp = (lp >= 0) ? img[lp] : 0.0f;
      unsigned cm = (Lm == 1.0f) ? (unsigned)tmpm[o]
                                 : (0x8000u | (Lm == 3.0f ? 1u : 0u));
      unsigned cp = (Lp == 1.0f) ? (unsigned)tmpp[o]
                                 : (0x8000u | (Lp == 3.0f ? 1u : 0u));
      list[p] = (unsigned short)o;
      aux[p]  = cm | (cp << 16);
      p++;
    }
    __syncthreads();
    if (cb == 0) cntB = (int)tot; else cntR = (int)tot;
  }

  // ---- channel offsets (iface z: planes z-1|z; iface z+1: z|z+1) ----
  const size_t offRm = ((size_t)z * 2 + 0) * SLOT;        // read from z-1 (L)
  const size_t offPm = ((size_t)z * 2 + 1) * SLOT;        // my publish (H)
  const size_t offRp = ((size_t)(z + 1) * 2 + 1) * SLOT;  // read from z+1 (H)
  const size_t offPp = ((size_t)(z + 1) * 2 + 0) * SLOT;  // my publish (L)

  // ---- prefill pr0 red-dyn slots with the initial value (gm init = 0) ----
  for (int p = tid; p < cntR; p += NTHR) {
    unsigned u = auxR[p];
    unsigned cm = u & 0xFFFFu, cp = u >> 16;
    if (!(cm & 0x8000u)) cstoref(&pr0[offPm + cm], 0.0f);
    if (!(cp & 0x8000u)) cstoref(&pr0[offPp + cp], 0.0f);
  }
  __syncthreads();                         // drain prefill
  // ---- startup barrier (count-only, 16 lines) ----
  if (tid == 0)
    __hip_atomic_fetch_add(&ctrl[(128u + (unsigned)(bid & 15)) * 16u], 1ull,
                           __ATOMIC_RELAXED, __HIP_MEMORY_SCOPE_AGENT);
  if (tid < 16) {
    for (;;) {
      unsigned long long v = cloadu(&ctrl[(128u + (unsigned)tid) * 16u]);
      v += __shfl_xor(v, 1, 64);  v += __shfl_xor(v, 2, 64);
      v += __shfl_xor(v, 4, 64);  v += __shfl_xor(v, 8, 64);
      if (v >= (unsigned long long)NBLK) break;
      __builtin_amdgcn_s_sleep(1);
    }
  }
  __syncthreads();

  const double WOPT = 2.0 / (1.0 + 3.14159265358979323846 / 66.0);

  int itout = 0;
  double dvout = 0.0;

  for (int t = 1; t <= 555; ++t) {
    const float* __restrict__ prold = (t & 1) ? pr0 : pr1;  // pr[(t-1)&1]
    float* __restrict__ pbcur       = (t & 1) ? pb1 : pb0;  // pb[t&1]
    float* __restrict__ prcur       = (t & 1) ? pr1 : pr0;  // pr[t&1]

    // ---- start-of-iter parallel waits + lagged stop decision ----
    if (t > 1) {
      const int g = t - 2;
      if (wid == 0 && lane < 2) {           // wave 0: neighbor red flags
        int nb = (lane == 0) ? (bid - 1) : (bid + 1);
        if (nb >= 0 && nb < NBLK) {
          while (cloadu(&ctrl[(276u + (unsigned)nb) * 16u])
                 < (unsigned long long)(t - 1))
            __builtin_amdgcn_s_sleep(1);
        }
      }
      if (g >= 1 && wid == 1 && lane < 16) { // wave 1: dv ring poll
        const int r = g & 7;
        const unsigned n = ((unsigned)g + 7u) >> 3;
        const unsigned long long t64 =
            ((unsigned long long)NBLK * n) << 44;
        unsigned long long v;
        for (;;) {
          v = cloadu(&ctrl[((unsigned)r * 16u + (unsigned)lane) * 16u]);
          v += __shfl_xor(v, 1, 64);  v += __shfl_xor(v, 2, 64);
          v += __shfl_xor(v, 4, 64);  v += __shfl_xor(v, 8, 64);
          if (v >= t64) break;
          __builtin_amdgcn_s_sleep(1);
        }
        if (lane == 0) {
          unsigned long long cum = v & MASK44;
          sh_dv = (double)(cum - prevs[r]) * (1.0 / 1048576.0);
          prevs[r] = cum;
        }
      }
      __syncthreads();
      if (g >= 1) {
        double dvg = sh_dv;
        if (!((dvg >= 0.05) && (g <= 500))) { itout = g; dvout = dvg; break; }
      }
    }

    double acc = 0.0;
    // ================= BLACK sweep =================
    if (tid < nM) HM[tid] = cloadf(&prold[offRm + tid]);
    if (tid < nP) HP[tid] = cloadf(&prold[offRp + tid]);
    __syncthreads();
    {
      float* __restrict__ wm = pbcur + offPm;
      float* __restrict__ wp = pbcur + offPp;
      for (int p = tid; p < cntB; p += NTHR) {
        const int o = (int)lsB[p];
        const unsigned u = auxB[p];
        const unsigned cm = u & 0xFFFFu, cp = u >> 16;
        double fzm = (cm & 0x8000u) ? (double)(cm & 1u) : (double)HM[cm];
        double fzp = (cp & 0x8000u) ? (double)(cp & 1u) : (double)HP[cp];
        double xi = P1[o];
        double nb = ((((P1[o - 1] + P1[o + 1]) + P1[o - NJK]) + P1[o + NJK])
                    + fzm) + fzp;
        double adj = (WOPT * (nb - 6.0 * xi)) / 6.0;
        double v = xi + adj;
        P1[o] = v;
        if (!(cm & 0x8000u)) cstoref(&wm[cm], (float)v);
        if (!(cp & 0x8000u)) cstoref(&wp[cp], (float)v);
        acc += fabs(adj);
      }
    }
    __syncthreads();                       // LDS visible + publishes drained
    if (tid == 0)
      cstoreu(&ctrl[(144u + (unsigned)bid) * 16u], (unsigned long long)t);
    if (tid < 2) {                         // wait neighbors' black publish
      int nb = (tid == 0) ? (bid - 1) : (bid + 1);
      if (nb >= 0 && nb < NBLK) {
        while (cloadu(&ctrl[(144u + (unsigned)nb) * 16u])
               < (unsigned long long)t)
          __builtin_amdgcn_s_sleep(1);
      }
    }
    __syncthreads();

    // ================= RED sweep =================
    if (tid < nM) HM[tid] = cloadf(&pbcur[offRm + tid]);
    if (tid < nP) HP[tid] = cloadf(&pbcur[offRp + tid]);
    __syncthreads();
    {
      float* __restrict__ wm = prcur + offPm;
      float* __restrict__ wp = prcur + offPp;
      for (int p = tid; p < cntR; p += NTHR) {
        const int o = (int)lsR[p];
        const unsigned u = auxR[p];
        const unsigned cm = u & 0xFFFFu, cp = u >> 16;
        double fzm = (cm & 0x8000u) ? (double)(cm & 1u) : (double)HM[cm];
        double fzp = (cp & 0x8000u) ? (double)(cp & 1u) : (double)HP[cp];
        double xi = P1[o];
        double nb = ((((P1[o - 1] + P1[o + 1]) + P1[o - NJK]) + P1[o + NJK])
                    + fzm) + fzp;
        double adj = (WOPT * (nb - 6.0 * xi)) / 6.0;
        double v = xi + adj;
        P1[o] = v;
        if (!(cm & 0x8000u)) cstoref(&wm[cm], (float)v);
        if (!(cp & 0x8000u)) cstoref(&wp[cp], (float)v);
        acc += fabs(adj);
      }
    }

    // ---- block dv reduce (fixed order) + flag + ring post ----
    double a = acc;
    #pragma unroll
    for (int m = 32; m >= 1; m >>= 1) a += __shfl_xor(a, m, 64);
    if (lane == 0) redw[wid] = a;
    __syncthreads();                       // drains red publish; redw ready
    if (tid == 0) {
      double s = redw[0];
      #pragma unroll
      for (int w = 1; w < NW; ++w) s += redw[w];
      cstoreu(&ctrl[(276u + (unsigned)bid) * 16u], (unsigned long long)t);
      __hip_atomic_fetch_add(
          &ctrl[(((unsigned)t & 7u) * 16u + (unsigned)(bid & 15)) * 16u],
          CNT1 + (unsigned long long)(s * 1048576.0 + 0.5),
          __ATOMIC_RELAXED, __HIP_MEMORY_SCOPE_AGENT);
    }
  }

  // ---- epilogue: lap straight from LDS (crop pad), + iters + dv ----
  {
    const int vb = (z >= 66) ? 1 : 0;
    const int pz = z - 66 * vb;
    if (pz >= 1 && pz <= 64) {
      float* ob = out + ((size_t)vb * 64 + (pz - 1)) * 4096;
      for (int t2 = tid; t2 < 4096; t2 += NTHR) {
        int jj = t2 >> 6, kk = t2 & 63;
        ob[t2] = (float)P1[NJK * (jj + 1) + (kk + 1)];
      }
    }
    if (z == 0 && tid == 0) {
      out[NOUT]     = (float)itout;
      out[NOUT + 1] = (float)dvout;
    }
  }
}

extern "C" void kernel_launch(void* const* d_in, const int* in_sizes, int n_in,
                              void* d_out, int out_size, void* d_ws, size_t ws_size,
                              hipStream_t stream) {
  const float* img = (const float*)d_in[0];
  float* out = (float*)d_out;
  const size_t CH_ELEMS = (size_t)NIF * 2 * SLOT;
  float* pb0 = (float*)d_ws;
  float* pb1 = pb0 + CH_ELEMS;
  float* pr0 = pb1 + CH_ELEMS;
  float* pr1 = pr0 + CH_ELEMS;
  unsigned long long* ctrl = (unsigned long long*)(pr1 + CH_ELEMS);

  sor_init_ctrl<<<1, 256, 0, stream>>>(ctrl);
  sor_main<<<NBLK, NTHR, 0, stream>>>(img, pb0, pb1, pr0, pr1, ctrl, out);
}